// Round 1
// baseline (49.126 us; speedup 1.0000x reference)
//
#include <hip/hip_runtime.h>

// Clustering layer: q[n,k] = t-dist kernel of ||z_n - c_k||^2, row-normalized.
// N=131072, K=100 (pad->112), D=256. f32 in/out; f16 MFMA for the dot products.
//
// d2 = ||z||^2 + ||c||^2 - 2 z.c  via  GEMM z @ c^T  (mfma_f32_16x16x32_f16)
// Memory-bound: ~187 MB HBM -> ~30us floor.

typedef __attribute__((ext_vector_type(8))) _Float16 f16x8;
typedef __attribute__((ext_vector_type(4))) _Float16 f16x4;
typedef __attribute__((ext_vector_type(4))) float    f32x4;

#define DDIM 256
#define KCL  100
#define KPAD 112   // 7 * 16
#define NT   7     // column tiles of 16

// ---------------- kernel 1: clusters f32 -> f16 (padded) + ||c||^2 ----------
__global__ __launch_bounds__(64) void prep_clusters(const float* __restrict__ c,
                                                    _Float16* __restrict__ cb,
                                                    float* __restrict__ c2) {
    const int r    = blockIdx.x;    // 0..111
    const int lane = threadIdx.x;   // 0..63, each lane handles 4 elems
    f32x4 v = {0.f, 0.f, 0.f, 0.f};
    if (r < KCL) {
        v = reinterpret_cast<const f32x4*>(c)[r * (DDIM / 4) + lane];
    }
    f16x4 b;
    b[0] = (_Float16)v[0]; b[1] = (_Float16)v[1];
    b[2] = (_Float16)v[2]; b[3] = (_Float16)v[3];
    reinterpret_cast<f16x4*>(cb)[r * (DDIM / 4) + lane] = b;

    float ss = v[0]*v[0] + v[1]*v[1] + v[2]*v[2] + v[3]*v[3];
    #pragma unroll
    for (int m = 1; m < 64; m <<= 1) ss += __shfl_xor(ss, m);
    if (lane == 0) c2[r] = ss;
}

// ---------------- kernel 2: main fused GEMM + epilogue -----------------------
// Block = 256 threads = 4 waves. Each wave: 64 rows x 112 cols (4x7 MFMA tiles).
// Grid = N/256 blocks.
__global__ __launch_bounds__(256, 2) void cluster_q(const float* __restrict__ z,
                                                    const _Float16* __restrict__ cb,
                                                    const float* __restrict__ c2,
                                                    float* __restrict__ out) {
    const int lane = threadIdx.x & 63;
    const int wv   = threadIdx.x >> 6;     // 0..3
    const int g    = lane >> 4;            // k-group 0..3
    const int c16  = lane & 15;            // row (A) / col (B) within tile
    const long rowbase = (long)blockIdx.x * 256 + wv * 64;

    f32x4 acc[4][NT];
    #pragma unroll
    for (int i = 0; i < 4; ++i)
        #pragma unroll
        for (int t = 0; t < NT; ++t)
            acc[i][t] = f32x4{0.f, 0.f, 0.f, 0.f};

    float zsq[4] = {0.f, 0.f, 0.f, 0.f};

    const float* zb = z + rowbase * DDIM;

    // K loop: 8 steps of 32. A from global f32 (convert), B from f16 workspace.
    // NOTE: A and B use identical (group,reg)->k indexing, so the hardware's
    // internal k-slot convention cancels out; only C/D layout matters below.
    #pragma unroll 1
    for (int s = 0; s < 8; ++s) {
        const int koff = 32 * s + 8 * g;
        f16x8 a[4];
        #pragma unroll
        for (int i = 0; i < 4; ++i) {
            const float* p = zb + (i * 16 + c16) * DDIM + koff;
            f32x4 lo = *reinterpret_cast<const f32x4*>(p);
            f32x4 hi = *reinterpret_cast<const f32x4*>(p + 4);
            zsq[i] += lo[0]*lo[0] + lo[1]*lo[1] + lo[2]*lo[2] + lo[3]*lo[3]
                    + hi[0]*hi[0] + hi[1]*hi[1] + hi[2]*hi[2] + hi[3]*hi[3];
            f16x8 av;
            av[0] = (_Float16)lo[0]; av[1] = (_Float16)lo[1];
            av[2] = (_Float16)lo[2]; av[3] = (_Float16)lo[3];
            av[4] = (_Float16)hi[0]; av[5] = (_Float16)hi[1];
            av[6] = (_Float16)hi[2]; av[7] = (_Float16)hi[3];
            a[i] = av;
        }
        f16x8 b[NT];
        #pragma unroll
        for (int t = 0; t < NT; ++t)
            b[t] = *reinterpret_cast<const f16x8*>(cb + (t * 16 + c16) * DDIM + koff);

        #pragma unroll
        for (int i = 0; i < 4; ++i)
            #pragma unroll
            for (int t = 0; t < NT; ++t)
                acc[i][t] = __builtin_amdgcn_mfma_f32_16x16x32_f16(a[i], b[t], acc[i][t], 0, 0, 0);
    }

    // ||z_row||^2: lane covered row (i*16 + c16), 64 of its 256 k-elems.
    // Sum the 4 k-groups (lanes differing in bits 4..5).
    #pragma unroll
    for (int i = 0; i < 4; ++i) {
        zsq[i] += __shfl_xor(zsq[i], 16);
        zsq[i] += __shfl_xor(zsq[i], 32);
    }
    // now lane l holds z2 of row (l & 15) for each tile i

    float c2v[NT];
    #pragma unroll
    for (int t = 0; t < NT; ++t) c2v[t] = c2[t * 16 + c16];

    // Epilogue. C/D layout (verified, guide §3): col = lane&15, row = g*4 + reg.
    #pragma unroll
    for (int i = 0; i < 4; ++i) {
        #pragma unroll
        for (int j = 0; j < 4; ++j) {
            const int r = 4 * g + j;                 // row within 16-tile
            const float z2 = __shfl(zsq[i], r);      // lane r holds row r's norm
            float qv[NT];
            float rs = 0.f;
            #pragma unroll
            for (int t = 0; t < NT; ++t) {
                const float dot = acc[i][t][j];
                const float d2 = fmaxf(z2 + c2v[t] - 2.f * dot, 0.f);
                const float q = __builtin_amdgcn_rcpf(1.f + d2);
                qv[t] = q;
                if (t < 6 || c16 < 4) rs += q;       // mask padded cols 100..111
            }
            // row sum across the 16 lanes of this group (cols)
            rs += __shfl_xor(rs, 1);
            rs += __shfl_xor(rs, 2);
            rs += __shfl_xor(rs, 4);
            rs += __shfl_xor(rs, 8);
            const float rinv = __builtin_amdgcn_rcpf(rs);

            float* orow = out + (rowbase + i * 16 + r) * KCL;
            #pragma unroll
            for (int t = 0; t < NT; ++t) {
                const int col = t * 16 + c16;
                if (col < KCL) orow[col] = qv[t] * rinv;
            }
        }
    }
}

// ---------------- launcher ---------------------------------------------------
extern "C" void kernel_launch(void* const* d_in, const int* in_sizes, int n_in,
                              void* d_out, int out_size, void* d_ws, size_t ws_size,
                              hipStream_t stream) {
    const float* z  = (const float*)d_in[0];
    const float* cl = (const float*)d_in[1];
    float* out = (float*)d_out;

    _Float16* cb = (_Float16*)d_ws;                                  // 112*256*2 B
    float*    c2 = (float*)((char*)d_ws + KPAD * DDIM * sizeof(_Float16));

    const int N = in_sizes[0] / DDIM;   // 131072

    prep_clusters<<<KPAD, 64, 0, stream>>>(cl, cb, c2);
    cluster_q<<<N / 256, 256, 0, stream>>>(z, cb, c2, out);
}